// Round 1
// baseline (802.495 us; speedup 1.0000x reference)
//
#include <hip/hip_runtime.h>
#include <math.h>

#define HD 1024
#define MD 4096
#define WD 4096
#define RD 4
#define NWD 2
#define MODESD 5
#define EPSF 0.001f

// ---- d_out offsets (floats), in reference return order ----
#define O_WORDS 0            // read_words   R*WD        = 16384
#define O_NM    16384        // new_memory   MD*WD       = 16777216
#define O_RW    16793600     // read_weights R*MD        = 16384
#define O_WW    16809984     // write_weights NW*MD      = 8192
#define O_LINK  16818176     // link         NW*MD*MD    = 33554432
#define O_PREC  50372608     // precedence   NW*MD       = 8192
#define O_USAGE 50380800     // usage        MD          = 4096

// ---- workspace offsets (floats) ----
#define WS_WV   0            // 8192
#define WS_EV   8192         // 8192 (sigmoid)
#define WS_WK   16384        // 8192 (sigmoid)
#define WS_RK   24576        // 16384
#define WS_FG   40960        // 4  (sigmoid)
#define WS_AG   40976        // 2  (sigmoid)
#define WS_WG   40992        // 2  (sigmoid)
#define WS_RM   41008        // 20 (sigmoid)
#define WS_WSTR 41040        // 2
#define WS_RS   41056        // 4
#define WS_UPRE 41104        // 4096 (usage pre-alloc; aliased as u1 after update0)
#define WS_SIM  45200        // NW*MD = 8192
#define WS_RDOT 53392        // R*MD  = 16384
#define WS_NMN  69776        // 4096
#define WS_CONT 73872        // R*MD  = 16384
#define WS_CW   123024       // NW*MD = 8192 (write content softmax)
#define WS_UU   131216       // 4096
#define WS_LU   135312       // 4096
// ---- zeroed region (single memset) ----
#define WS_S0    139408      // 4096 rank-product log-sum, head 0
#define WS_S1    143504      // 4096 rank-product log-sum, head 1
#define WS_WWSUM 147600      // 4 (2 used)
#define WS_BAR   147604      // 16 barrier counters (uint)
#define WS_FWD   147620      // R*NW*MD = 32768 (atomic targets)
#define WS_BWD   180388      // R*NW*MD = 32768 (atomic targets)
#define WS_ZERO_START WS_S0
#define WS_ZERO_COUNT (213156 - 139408)

typedef float floatx4 __attribute__((ext_vector_type(4)));

__device__ __forceinline__ float4 ntload4(const float4* p) {
  floatx4 t = __builtin_nontemporal_load((const floatx4*)p);
  float4 r; r.x = t.x; r.y = t.y; r.z = t.z; r.w = t.w;
  return r;
}
__device__ __forceinline__ void ntstore4(float4* p, float4 v) {
  floatx4 t; t.x = v.x; t.y = v.y; t.z = v.z; t.w = v.w;
  __builtin_nontemporal_store(t, (floatx4*)p);
}

__device__ __forceinline__ float waveReduceSum(float v) {
#pragma unroll
  for (int o = 32; o; o >>= 1) v += __shfl_down(v, o, 64);
  return v;
}

// ---------------- ALL GEMVs fused: 40960 big rows + 34 small rows ----------------
__global__ void __launch_bounds__(256) gemv_all_kernel(
    const float* __restrict__ x,
    const float* __restrict__ Wwv, const float* __restrict__ bwv,
    const float* __restrict__ Wev, const float* __restrict__ bev,
    const float* __restrict__ Wwk, const float* __restrict__ bwk,
    const float* __restrict__ Wrk, const float* __restrict__ brk,
    const float* __restrict__ Wfg, const float* __restrict__ bfg,
    const float* __restrict__ Wag, const float* __restrict__ bag,
    const float* __restrict__ Wwg, const float* __restrict__ bwg,
    const float* __restrict__ Wrm, const float* __restrict__ brm,
    const float* __restrict__ Wws, const float* __restrict__ bws,
    const float* __restrict__ Wrs, const float* __restrict__ brs,
    float* __restrict__ ws) {
  __shared__ float4 xs[HD / 4];
  int t = threadIdx.x;
  xs[t] = ((const float4*)x)[t];
  __syncthreads();
  int wave = t >> 6, lane = t & 63;
  int row = blockIdx.x * 4 + wave;
  if (row >= 40994) return;
  const float* W; const float* b; float* out; int r; int act;
  if (row < 8192)       { W = Wwv; b = bwv; out = ws + WS_WV;   r = row;         act = 0; }
  else if (row < 16384) { W = Wev; b = bev; out = ws + WS_EV;   r = row - 8192;  act = 1; }
  else if (row < 24576) { W = Wwk; b = bwk; out = ws + WS_WK;   r = row - 16384; act = 1; }
  else if (row < 40960) { W = Wrk; b = brk; out = ws + WS_RK;   r = row - 24576; act = 0; }
  else if (row < 40964) { W = Wfg; b = bfg; out = ws + WS_FG;   r = row - 40960; act = 1; }
  else if (row < 40966) { W = Wag; b = bag; out = ws + WS_AG;   r = row - 40964; act = 1; }
  else if (row < 40968) { W = Wwg; b = bwg; out = ws + WS_WG;   r = row - 40966; act = 1; }
  else if (row < 40988) { W = Wrm; b = brm; out = ws + WS_RM;   r = row - 40968; act = 1; }
  else if (row < 40990) { W = Wws; b = bws; out = ws + WS_WSTR; r = row - 40988; act = 0; }
  else                  { W = Wrs; b = brs; out = ws + WS_RS;   r = row - 40990; act = 0; }
  const float4* W4 = (const float4*)(W + (size_t)r * HD);
  float acc = 0.f;
#pragma unroll
  for (int i = 0; i < 4; ++i) {
    float4 w = ntload4(W4 + i * 64 + lane);
    float4 xv = xs[i * 64 + lane];
    acc += w.x * xv.x + w.y * xv.y + w.z * xv.z + w.w * xv.w;
  }
  acc = waveReduceSum(acc);
  if (lane == 0) {
    float v = acc + b[r];
    if (act) v = 1.f / (1.f + expf(-v));
    out[r] = v;
  }
}

// ---------------- write-key similarity over memory (wk norms inlined) ----------------
__global__ void sim_kernel(const float* __restrict__ mem, const float* __restrict__ wk,
                           float* __restrict__ sim) {
  int m = blockIdx.x;
  int t = threadIdx.x;
  const float4* row = (const float4*)(mem + (size_t)m * WD);
  const float4* k0 = (const float4*)wk;
  const float4* k1 = (const float4*)(wk + WD);
  float d0 = 0, d1 = 0, s = 0, n0 = 0, n1 = 0;
  for (int i = t; i < WD / 4; i += 256) {
    float4 v = row[i], a = k0[i], b = k1[i];
    d0 += v.x * a.x + v.y * a.y + v.z * a.z + v.w * a.w;
    d1 += v.x * b.x + v.y * b.y + v.z * b.z + v.w * b.w;
    s  += v.x * v.x + v.y * v.y + v.z * v.z + v.w * v.w;
    n0 += a.x * a.x + a.y * a.y + a.z * a.z + a.w * a.w;
    n1 += b.x * b.x + b.y * b.y + b.z * b.z + b.w * b.w;
  }
  d0 = waveReduceSum(d0); d1 = waveReduceSum(d1); s = waveReduceSum(s);
  n0 = waveReduceSum(n0); n1 = waveReduceSum(n1);
  __shared__ float sh[5][4];
  int wave = t >> 6, lane = t & 63;
  if (lane == 0) { sh[0][wave] = d0; sh[1][wave] = d1; sh[2][wave] = s; sh[3][wave] = n0; sh[4][wave] = n1; }
  __syncthreads();
  if (t == 0) {
    float D0 = sh[0][0] + sh[0][1] + sh[0][2] + sh[0][3];
    float D1 = sh[1][0] + sh[1][1] + sh[1][2] + sh[1][3];
    float S  = sh[2][0] + sh[2][1] + sh[2][2] + sh[2][3];
    float N0 = sh[3][0] + sh[3][1] + sh[3][2] + sh[3][3];
    float N1 = sh[4][0] + sh[4][1] + sh[4][2] + sh[4][3];
    float mn = sqrtf(S);
    sim[0 * MD + m] = D0 / (sqrtf(N0) * mn + EPSF);
    sim[1 * MD + m] = D1 / (sqrtf(N1) * mn + EPSF);
  }
}

// ---------------- write content softmax (per head) ----------------
__global__ void cw_kernel(const float* __restrict__ sim, const float* __restrict__ wstr,
                          float* __restrict__ cw) {
  int h = blockIdx.x;
  int t = threadIdx.x;
  __shared__ float vals[MD];
  __shared__ float red[256];
  float beta = 1.f + log1pf(expf(wstr[h]));
  float mx = -3.4e38f;
  for (int m = t; m < MD; m += 256) {
    float v = sim[h * MD + m] * beta;
    vals[m] = v; mx = fmaxf(mx, v);
  }
  red[t] = mx; __syncthreads();
  for (int s = 128; s; s >>= 1) { if (t < s) red[t] = fmaxf(red[t], red[t + s]); __syncthreads(); }
  mx = red[0]; __syncthreads();
  float sm = 0.f;
  for (int m = t; m < MD; m += 256) { float e = expf(vals[m] - mx); vals[m] = e; sm += e; }
  red[t] = sm; __syncthreads();
  for (int s = 128; s; s >>= 1) { if (t < s) red[t] += red[t + s]; __syncthreads(); }
  float inv = 1.f / red[0];
  for (int m = t; m < MD; m += 256) cw[h * MD + m] = vals[m] * inv;
}

// ---------------- fused allocation chain (usage, S0, upd0, S1, upd1, prec) ----------------
#define AB 64   // blocks — co-resident on 256 CUs, manual grid barrier is safe

__device__ __forceinline__ void gridbar(unsigned* c, int id) {
  __syncthreads();
  if (threadIdx.x == 0) {
    __threadfence();                       // release: make block's stores visible
    atomicAdd(&c[id], 1u);
    while (atomicAdd(&c[id], 0u) < AB) __builtin_amdgcn_s_sleep(8);
  }
  __syncthreads();
  __threadfence();                         // acquire: see other blocks' stores
}

__global__ void __launch_bounds__(256)
alloc_chain_kernel(const float* __restrict__ pusage, const float* __restrict__ pww,
                   const float* __restrict__ prw, const float* __restrict__ pprec,
                   float* __restrict__ ws, float* __restrict__ out_ww,
                   float* __restrict__ out_usage, float* __restrict__ out_prec) {
  float* upre = ws + WS_UPRE;
  float* uu = ws + WS_UU;
  float* lu = ws + WS_LU;
  float* S0 = ws + WS_S0;
  float* S1 = ws + WS_S1;
  float* wwsum = ws + WS_WWSUM;
  const float* cw = ws + WS_CW;
  const float* fg = ws + WS_FG;
  const float* ag = ws + WS_AG;
  const float* wg = ws + WS_WG;
  unsigned* bar = (unsigned*)(ws + WS_BAR);
  int tid = threadIdx.x;
  int idx = blockIdx.x * 256 + tid;
  __shared__ float lds_u[1024], lds_l[1024];

  // Phase 0: usage pre-allocation + uu/logu (head 0)
  if (idx < MD) {
    float pw = pww[idx] * pww[MD + idx];
    float pu = pusage[idx];
    float u = pu + (1.f - pu) * (1.f - pw);
    float pr = 1.f;
#pragma unroll
    for (int r = 0; r < RD; ++r) pr *= fg[r] * prw[r * MD + idx];
    float up = u * (1.f - pr);
    upre[idx] = up;
    float v = EPSF + (1.f - EPSF) * up;
    uu[idx] = v;
    lu[idx] = logf(v);
  }
  gridbar(bar, 0);

  // Phase 1: S0 rank-product partial sums (i: 4096, each block owns a j-quarter)
  {
    int jq = blockIdx.x >> 4;                 // 0..3
    int i = ((blockIdx.x & 15) << 8) + tid;   // 0..4095
    int j0 = jq << 10;
    for (int k = tid; k < 1024; k += 256) { lds_u[k] = uu[j0 + k]; lds_l[k] = lu[j0 + k]; }
    __syncthreads();
    float ui = uu[i];
    float s = 0.f;
#pragma unroll 4
    for (int k = 0; k < 1024; ++k) {
      int j = j0 + k;
      float uj = lds_u[k];
      s += ((uj < ui) || (uj == ui && j < i)) ? lds_l[k] : 0.f;
    }
    atomicAdd(&S0[i], s);
  }
  gridbar(bar, 1);

  // Phase 2: head-0 update (a0, ww0, usage1, uu/logu for head 1)
  if (idx < MD) {
    float agv = ag[0], wgv = wg[0];
    float uum = uu[idx];
    float a = (1.f - uum) * expf(S0[idx]);
    float w = wgv * (agv * a + (1.f - agv) * cw[idx]);
    out_ww[idx] = w;
    float up = upre[idx];
    float un = up + (1.f - up) * (agv * wgv) * a;
    upre[idx] = un;                // aliased as u1 — same-thread rmw, safe
    float v = EPSF + (1.f - EPSF) * un;
    uu[idx] = v;
    lu[idx] = logf(v);
    float p = waveReduceSum(w);
    if ((tid & 63) == 0) atomicAdd(&wwsum[0], p);
  }
  gridbar(bar, 2);

  // Phase 3: S1
  {
    int jq = blockIdx.x >> 4;
    int i = ((blockIdx.x & 15) << 8) + tid;
    int j0 = jq << 10;
    for (int k = tid; k < 1024; k += 256) { lds_u[k] = uu[j0 + k]; lds_l[k] = lu[j0 + k]; }
    __syncthreads();
    float ui = uu[i];
    float s = 0.f;
#pragma unroll 4
    for (int k = 0; k < 1024; ++k) {
      int j = j0 + k;
      float uj = lds_u[k];
      s += ((uj < ui) || (uj == ui && j < i)) ? lds_l[k] : 0.f;
    }
    atomicAdd(&S1[i], s);
  }
  gridbar(bar, 3);

  // Phase 4: head-1 update (a1, ww1, final usage)
  if (idx < MD) {
    float agv = ag[1], wgv = wg[1];
    float uum = uu[idx];
    float a = (1.f - uum) * expf(S1[idx]);
    float w = wgv * (agv * a + (1.f - agv) * cw[MD + idx]);
    out_ww[MD + idx] = w;
    float un = upre[idx];
    out_usage[idx] = un + (1.f - un) * (agv * wgv) * a;
    float p = waveReduceSum(w);
    if ((tid & 63) == 0) atomicAdd(&wwsum[1], p);
  }
  gridbar(bar, 4);

  // Phase 5: precedence
  if (idx < MD) {
    float s0 = wwsum[0], s1 = wwsum[1];
    out_prec[idx] = (1.f - s0) * pprec[idx] + out_ww[idx];
    out_prec[MD + idx] = (1.f - s1) * pprec[MD + idx] + out_ww[MD + idx];
  }
}

// ---------------- new_memory + fused rdot + new norms ----------------
__global__ void newmem_kernel(const float* __restrict__ mem, const float* __restrict__ ww,
                              const float* __restrict__ ev, const float* __restrict__ wvv,
                              const float* __restrict__ rk, float* __restrict__ nm_out,
                              float* __restrict__ rdot, float* __restrict__ nmn) {
  int m = blockIdx.x;
  int t = threadIdx.x;
  float w0 = ww[m], w1 = ww[MD + m];
  const float4* row = (const float4*)(mem + (size_t)m * WD);
  const float4* e0 = (const float4*)ev;
  const float4* e1 = (const float4*)(ev + WD);
  const float4* v0 = (const float4*)wvv;
  const float4* v1 = (const float4*)(wvv + WD);
  const float4* k0 = (const float4*)rk;
  const float4* k1 = (const float4*)(rk + WD);
  const float4* k2 = (const float4*)(rk + 2 * WD);
  const float4* k3 = (const float4*)(rk + 3 * WD);
  float4* outp = (float4*)(nm_out + (size_t)m * WD);
  float r0 = 0, r1 = 0, r2 = 0, r3 = 0, s2 = 0;
  for (int i = t; i < WD / 4; i += 256) {
    float4 mv = row[i], ea = e0[i], eb = e1[i], va = v0[i], vb = v1[i];
    float4 o;
    o.x = mv.x * (1.f - w0 * ea.x) * (1.f - w1 * eb.x) + w0 * va.x + w1 * vb.x;
    o.y = mv.y * (1.f - w0 * ea.y) * (1.f - w1 * eb.y) + w0 * va.y + w1 * vb.y;
    o.z = mv.z * (1.f - w0 * ea.z) * (1.f - w1 * eb.z) + w0 * va.z + w1 * vb.z;
    o.w = mv.w * (1.f - w0 * ea.w) * (1.f - w1 * eb.w) + w0 * va.w + w1 * vb.w;
    outp[i] = o;
    float4 a = k0[i]; r0 += o.x * a.x + o.y * a.y + o.z * a.z + o.w * a.w;
    float4 b = k1[i]; r1 += o.x * b.x + o.y * b.y + o.z * b.z + o.w * b.w;
    float4 c = k2[i]; r2 += o.x * c.x + o.y * c.y + o.z * c.z + o.w * c.w;
    float4 d = k3[i]; r3 += o.x * d.x + o.y * d.y + o.z * d.z + o.w * d.w;
    s2 += o.x * o.x + o.y * o.y + o.z * o.z + o.w * o.w;
  }
  r0 = waveReduceSum(r0); r1 = waveReduceSum(r1); r2 = waveReduceSum(r2);
  r3 = waveReduceSum(r3); s2 = waveReduceSum(s2);
  __shared__ float sh[5][4];
  int wave = t >> 6, lane = t & 63;
  if (lane == 0) { sh[0][wave] = r0; sh[1][wave] = r1; sh[2][wave] = r2; sh[3][wave] = r3; sh[4][wave] = s2; }
  __syncthreads();
  if (t == 0) {
    rdot[0 * MD + m] = sh[0][0] + sh[0][1] + sh[0][2] + sh[0][3];
    rdot[1 * MD + m] = sh[1][0] + sh[1][1] + sh[1][2] + sh[1][3];
    rdot[2 * MD + m] = sh[2][0] + sh[2][1] + sh[2][2] + sh[2][3];
    rdot[3 * MD + m] = sh[3][0] + sh[3][1] + sh[3][2] + sh[3][3];
    nmn[m] = sqrtf(sh[4][0] + sh[4][1] + sh[4][2] + sh[4][3]);
  }
}

// ---------------- content softmax per read head (rk norms inlined) ----------------
__global__ void content_kernel(const float* __restrict__ rdot, const float* __restrict__ nmn,
                               const float* __restrict__ rk, const float* __restrict__ rs,
                               float* __restrict__ cont) {
  int r = blockIdx.x;
  int t = threadIdx.x;
  __shared__ float vals[MD];
  __shared__ float red[256];
  const float* kr = rk + (size_t)r * WD;
  float s2 = 0.f;
  for (int d = t; d < WD; d += 256) { float v = kr[d]; s2 += v * v; }
  red[t] = s2; __syncthreads();
  for (int s = 128; s; s >>= 1) { if (t < s) red[t] += red[t + s]; __syncthreads(); }
  float kn = sqrtf(red[0]); __syncthreads();
  float strength = rs[r];
  float mx = -3.4e38f;
  for (int m = t; m < MD; m += 256) {
    float v = rdot[r * MD + m] / (kn * nmn[m]) * strength;
    vals[m] = v; mx = fmaxf(mx, v);
  }
  red[t] = mx; __syncthreads();
  for (int s = 128; s; s >>= 1) { if (t < s) red[t] = fmaxf(red[t], red[t + s]); __syncthreads(); }
  mx = red[0]; __syncthreads();
  float sm = 0.f;
  for (int m = t; m < MD; m += 256) { float e = expf(vals[m] - mx); vals[m] = e; sm += e; }
  red[t] = sm; __syncthreads();
  for (int s = 128; s; s >>= 1) { if (t < s) red[t] += red[t + s]; __syncthreads(); }
  float inv = 1.f / red[0];
  for (int m = t; m < MD; m += 256) cont[r * MD + m] = vals[m] * inv;
}

// ---------------- link + fwd row-sums + bwd col-sums, single pass over plink ----------------
#define LMT 64   // m-tile; grid (64, 4, 2) = 512 blocks
__global__ void __launch_bounds__(256) link_fused_kernel(
    const float* __restrict__ plink, const float* __restrict__ ww,
    const float* __restrict__ pprec, const float* __restrict__ prw,
    float* __restrict__ link_out, float* __restrict__ fwd, float* __restrict__ bwd) {
  int mc = blockIdx.x, jc = blockIdx.y, w = blockIdx.z;
  int tid = threadIdx.x;
  __shared__ float ww_s[LMT];
  __shared__ float prw_s[4][LMT];
  __shared__ float fwd_s[LMT][4];
  int m0 = mc * LMT;
  for (int k = tid; k < LMT; k += 256) {
    ww_s[k] = ww[w * MD + m0 + k];
    prw_s[0][k] = prw[0 * MD + m0 + k];
    prw_s[1][k] = prw[1 * MD + m0 + k];
    prw_s[2][k] = prw[2 * MD + m0 + k];
    prw_s[3][k] = prw[3 * MD + m0 + k];
  }
  for (int k = tid; k < LMT * 4; k += 256) ((float*)fwd_s)[k] = 0.f;
  __syncthreads();
  int j0 = jc * 1024 + tid * 4;
  float4 wwj = *(const float4*)(ww + w * MD + j0);
  float4 pj  = *(const float4*)(pprec + w * MD + j0);
  float4 q0  = *(const float4*)(prw + 0 * MD + j0);
  float4 q1  = *(const float4*)(prw + 1 * MD + j0);
  float4 q2  = *(const float4*)(prw + 2 * MD + j0);
  float4 q3  = *(const float4*)(prw + 3 * MD + j0);
  float4 a0 = make_float4(0.f, 0.f, 0.f, 0.f), a1 = a0, a2 = a0, a3 = a0;
  int lane = tid & 63;
  const size_t base = (size_t)w * MD * MD;
#pragma unroll 2
  for (int mi = 0; mi < LMT; ++mi) {
    int mg = m0 + mi;
    float wwi = ww_s[mi];
    float4 L = ntload4((const float4*)(plink + base + (size_t)mg * MD + j0));
    float4 o;
    o.x = (1.f - wwi - wwj.x) * L.x + wwi * pj.x;
    o.y = (1.f - wwi - wwj.y) * L.y + wwi * pj.y;
    o.z = (1.f - wwi - wwj.z) * L.z + wwi * pj.z;
    o.w = (1.f - wwi - wwj.w) * L.w + wwi * pj.w;
    int dj = mg - j0;                 // diagonal zero — branchless (no dyn-indexed reg array)
    o.x = (dj == 0) ? 0.f : o.x;
    o.y = (dj == 1) ? 0.f : o.y;
    o.z = (dj == 2) ? 0.f : o.z;
    o.w = (dj == 3) ? 0.f : o.w;
    ntstore4((float4*)(link_out + base + (size_t)mg * MD + j0), o);
    float pm0 = prw_s[0][mi], pm1 = prw_s[1][mi], pm2 = prw_s[2][mi], pm3 = prw_s[3][mi];
    a0.x += pm0 * o.x; a0.y += pm0 * o.y; a0.z += pm0 * o.z; a0.w += pm0 * o.w;
    a1.x += pm1 * o.x; a1.y += pm1 * o.y; a1.z += pm1 * o.z; a1.w += pm1 * o.w;
    a2.x += pm2 * o.x; a2.y += pm2 * o.y; a2.z += pm2 * o.z; a2.w += pm2 * o.w;
    a3.x += pm3 * o.x; a3.y += pm3 * o.y; a3.z += pm3 * o.z; a3.w += pm3 * o.w;
    float s0 = o.x * q0.x + o.y * q0.y + o.z * q0.z + o.w * q0.w;
    float s1 = o.x * q1.x + o.y * q1.y + o.z * q1.z + o.w * q1.w;
    float s2 = o.x * q2.x + o.y * q2.y + o.z * q2.z + o.w * q2.w;
    float s3 = o.x * q3.x + o.y * q3.y + o.z * q3.z + o.w * q3.w;
#pragma unroll
    for (int off = 32; off; off >>= 1) {
      s0 += __shfl_down(s0, off, 64);
      s1 += __shfl_down(s1, off, 64);
      s2 += __shfl_down(s2, off, 64);
      s3 += __shfl_down(s3, off, 64);
    }
    if (lane == 0) {
      atomicAdd(&fwd_s[mi][0], s0);
      atomicAdd(&fwd_s[mi][1], s1);
      atomicAdd(&fwd_s[mi][2], s2);
      atomicAdd(&fwd_s[mi][3], s3);
    }
  }
  __syncthreads();
  for (int k = tid; k < LMT * 4; k += 256) {
    int mi = k >> 2, r = k & 3;
    atomicAdd(&fwd[(r * NWD + w) * MD + m0 + mi], fwd_s[mi][r]);
  }
  float* b0 = bwd + (size_t)(0 * NWD + w) * MD + j0;
  float* b1 = bwd + (size_t)(1 * NWD + w) * MD + j0;
  float* b2 = bwd + (size_t)(2 * NWD + w) * MD + j0;
  float* b3 = bwd + (size_t)(3 * NWD + w) * MD + j0;
  atomicAdd(b0 + 0, a0.x); atomicAdd(b0 + 1, a0.y); atomicAdd(b0 + 2, a0.z); atomicAdd(b0 + 3, a0.w);
  atomicAdd(b1 + 0, a1.x); atomicAdd(b1 + 1, a1.y); atomicAdd(b1 + 2, a1.z); atomicAdd(b1 + 3, a1.w);
  atomicAdd(b2 + 0, a2.x); atomicAdd(b2 + 1, a2.y); atomicAdd(b2 + 2, a2.z); atomicAdd(b2 + 3, a2.w);
  atomicAdd(b3 + 0, a3.x); atomicAdd(b3 + 1, a3.y); atomicAdd(b3 + 2, a3.z); atomicAdd(b3 + 3, a3.w);
}

// ---------------- final read weights ----------------
__global__ void rw_kernel(const float* __restrict__ fwd, const float* __restrict__ bwd,
                          const float* __restrict__ cont, const float* __restrict__ rm,
                          float* __restrict__ out_rw) {
  int idx = blockIdx.x * 256 + threadIdx.x;  // r*MD + m
  int r = idx >> 12;
  int m = idx & (MD - 1);
  float v = rm[r * MODESD + 4] * cont[idx];
#pragma unroll
  for (int w = 0; w < NWD; ++w) {
    v += rm[r * MODESD + w] * bwd[(r * NWD + w) * MD + m];
    v += rm[r * MODESD + NWD + w] * fwd[(r * NWD + w) * MD + m];
  }
  out_rw[idx] = v;
}

// ---------------- read words ----------------
__global__ void rwords_kernel(const float* __restrict__ rw, const float* __restrict__ nm,
                              float* __restrict__ out_words) {
  int mc = blockIdx.x;
  int d = blockIdx.y * 256 + threadIdx.x;
  float a0 = 0, a1 = 0, a2 = 0, a3 = 0;
  int m0 = mc * 256;
  for (int m = m0; m < m0 + 256; ++m) {
    float v = nm[(size_t)m * WD + d];
    a0 += rw[m] * v;
    a1 += rw[MD + m] * v;
    a2 += rw[2 * MD + m] * v;
    a3 += rw[3 * MD + m] * v;
  }
  atomicAdd(&out_words[d], a0);
  atomicAdd(&out_words[WD + d], a1);
  atomicAdd(&out_words[2 * WD + d], a2);
  atomicAdd(&out_words[3 * WD + d], a3);
}

extern "C" void kernel_launch(void* const* d_in, const int* in_sizes, int n_in,
                              void* d_out, int out_size, void* d_ws, size_t ws_size,
                              hipStream_t stream) {
  (void)in_sizes; (void)n_in; (void)out_size; (void)ws_size;
  const float* x      = (const float*)d_in[0];
  const float* memory = (const float*)d_in[1];
  const float* prw    = (const float*)d_in[2];
  const float* pww    = (const float*)d_in[3];
  const float* plink  = (const float*)d_in[4];
  const float* pprec  = (const float*)d_in[5];
  const float* pusage = (const float*)d_in[6];
  float* ws  = (float*)d_ws;
  float* out = (float*)d_out;

  hipMemsetAsync(ws + WS_ZERO_START, 0, WS_ZERO_COUNT * sizeof(float), stream);
  hipMemsetAsync(out + O_WORDS, 0, 16384 * sizeof(float), stream);

  // all GEMVs in one launch (NT weight loads)
  gemv_all_kernel<<<10249, 256, 0, stream>>>(x,
      (const float*)d_in[7],  (const float*)d_in[8],    // wv
      (const float*)d_in[9],  (const float*)d_in[10],   // ev
      (const float*)d_in[19], (const float*)d_in[20],   // wk
      (const float*)d_in[23], (const float*)d_in[24],   // rk
      (const float*)d_in[11], (const float*)d_in[12],   // fg
      (const float*)d_in[13], (const float*)d_in[14],   // ag
      (const float*)d_in[15], (const float*)d_in[16],   // wg
      (const float*)d_in[17], (const float*)d_in[18],   // rm
      (const float*)d_in[21], (const float*)d_in[22],   // wstr
      (const float*)d_in[25], (const float*)d_in[26],   // rs
      ws);

  sim_kernel<<<4096, 256, 0, stream>>>(memory, ws + WS_WK, ws + WS_SIM);
  cw_kernel<<<2, 256, 0, stream>>>(ws + WS_SIM, ws + WS_WSTR, ws + WS_CW);

  // entire allocation chain in one launch (manual grid barriers)
  alloc_chain_kernel<<<AB, 256, 0, stream>>>(pusage, pww, prw, pprec, ws,
                                             out + O_WW, out + O_USAGE, out + O_PREC);

  // memory is L3-hot from sim_kernel (only tiny kernels in between)
  newmem_kernel<<<4096, 256, 0, stream>>>(memory, out + O_WW, ws + WS_EV, ws + WS_WV,
                                          ws + WS_RK, out + O_NM, ws + WS_RDOT, ws + WS_NMN);
  content_kernel<<<4, 256, 0, stream>>>(ws + WS_RDOT, ws + WS_NMN, ws + WS_RK, ws + WS_RS, ws + WS_CONT);

  // single pass over plink: link + fwd + bwd (NT streams keep nm L3-resident)
  link_fused_kernel<<<dim3(64, 4, 2), 256, 0, stream>>>(plink, out + O_WW, pprec, prw,
                                                        out + O_LINK, ws + WS_FWD, ws + WS_BWD);
  rw_kernel<<<64, 256, 0, stream>>>(ws + WS_FWD, ws + WS_BWD, ws + WS_CONT, ws + WS_RM, out + O_RW);
  rwords_kernel<<<dim3(16, 16), 256, 0, stream>>>(out + O_RW, out + O_NM, out + O_WORDS);
}